// Round 12
// baseline (78.589 us; speedup 1.0000x reference)
//
#include <hip/hip_runtime.h>

#define BDIM 128
#define TDIM 512
#define DDIM 64
#define HDIM 256
#define BH   (BDIM * HDIM)            // 32768
#define HH_OFF (4 * BH)               // hh: B x 1024 after the 4 partial planes
#define HSTRIDE 260                   // padded LDS row stride (floats, 16B-aligned)

typedef short s16x8 __attribute__((ext_vector_type(8)));
typedef float f32x4 __attribute__((ext_vector_type(4)));

#if __has_builtin(__builtin_amdgcn_exp2f)
#define EXP2(x) __builtin_amdgcn_exp2f(x)
#else
#define EXP2(x) exp2f(x)
#endif
#define L2E 1.44269504f

__device__ __forceinline__ float rcpf(float x) { return __builtin_amdgcn_rcpf(x); }

__device__ __forceinline__ short f2bf(float f) {
  __bf16 b = (__bf16)f;
  return __builtin_bit_cast(short, b);
}

__device__ __forceinline__ s16x8 pack_bf8(float4 lo, float4 hi) {
  s16x8 v;
  v[0] = f2bf(lo.x); v[1] = f2bf(lo.y); v[2] = f2bf(lo.z); v[3] = f2bf(lo.w);
  v[4] = f2bf(hi.x); v[5] = f2bf(hi.y); v[6] = f2bf(hi.z); v[7] = f2bf(hi.w);
  return v;
}

__device__ __forceinline__ s16x8 pack_bf8s(float4 lo, float4 hi, float s) {
  s16x8 v;
  v[0] = f2bf(lo.x*s); v[1] = f2bf(lo.y*s); v[2] = f2bf(lo.z*s); v[3] = f2bf(lo.w*s);
  v[4] = f2bf(hi.x*s); v[5] = f2bf(hi.y*s); v[6] = f2bf(hi.z*s); v[7] = f2bf(hi.w*s);
  return v;
}

// hh[b][colw] = Whh[colw].h0[b] + bih + bhh — LDS-staged, b-batched GEMV.
// 64 blocks x 256 threads. Block c owns gate-cols [c*16,+16): stages those 16
// Whh rows (16KB) into padded LDS ONCE (coalesced), then loops 8 groups of
// 16 b reusing them. Thread = (b-local, col): whh reads are 4-lane broadcast
// 2-per-bank (free), h0 reads are 16-lane broadcast. Replaces the scattered
// row-per-thread GEMV that cost ~17-20us standalone (R4-R8) / +15us inline (R11).
__global__ __launch_bounds__(256) void hh2_kernel(
    const float* __restrict__ h0, const float* __restrict__ Whh,
    const float* __restrict__ bih, const float* __restrict__ bhh,
    float* __restrict__ hh)
{
  const int c = blockIdx.x, tid = threadIdx.x;
  __shared__ float whh_s[16 * HSTRIDE];
  __shared__ float h0s[16 * HSTRIDE];

  #pragma unroll
  for (int i = 0; i < 4; ++i) {          // 16 rows x 64 float4, coalesced
    int idx = i * 256 + tid;
    int row = idx >> 6, off = idx & 63;
    float4 v = *(const float4*)(Whh + (size_t)(c * 16 + row) * HDIM + off * 4);
    *(float4*)&whh_s[row * HSTRIDE + off * 4] = v;
  }

  const int bl  = tid >> 4;              // local b 0..15
  const int col = tid & 15;
  const int colw = c * 16 + col;
  const float bias = bih[colw] + bhh[colw];

  for (int grp = 0; grp < 8; ++grp) {
    __syncthreads();                     // protect h0s reuse across groups
    #pragma unroll
    for (int i = 0; i < 4; ++i) {
      int idx = i * 256 + tid;
      int row = idx >> 6, off = idx & 63;
      float4 v = *(const float4*)(h0 + (size_t)(grp * 16 + row) * HDIM + off * 4);
      *(float4*)&h0s[row * HSTRIDE + off * 4] = v;
    }
    __syncthreads();

    const float* wr = &whh_s[col * HSTRIDE];
    const float* hr = &h0s[bl * HSTRIDE];
    float acc = 0.f;
    #pragma unroll 8
    for (int k = 0; k < HDIM; k += 4) {
      float4 w  = *(const float4*)(wr + k);
      float4 hv = *(const float4*)(hr + k);
      acc += w.x * hv.x + w.y * hv.y + w.z * hv.z + w.w * hv.w;
    }
    hh[(size_t)(grp * 16 + bl) * 1024 + colw] = acc + bias;
  }
}

// Grid: (128, 8), 512 threads = 8 waves, zero in-loop barriers.
// EXACT R8 structure (fastest measured fused body, 51.5us): hh from global
// (precomputed), w0/w1 via __shfl from A-tile registers, 1-deep prefetch.
__global__ __launch_bounds__(512, 4) void fused_lstm(
    const float* __restrict__ x, const float* __restrict__ c0,
    const float* __restrict__ Wih, const int* __restrict__ longp,
    float* __restrict__ sbuf)
{
  const int b    = blockIdx.x;
  const int hcq  = blockIdx.y;          // 0..7
  const int tid  = threadIdx.x;
  const int wave = tid >> 6;            // 0..7
  const int lane = tid & 63;
  const int col  = lane & 15;
  const int kg   = lane >> 4;           // 0..3
  const int hp   = wave & 1;
  const int tq   = wave >> 1;           // 0..3
  const int h    = hcq * 32 + hp * 16 + col;

  __shared__ float red[8 * 64];

  const float* hh = sbuf + HH_OFF;
  const float* xb = x + (size_t)b * (TDIM * DDIM);
  const float inv_long = 1.0f / (float)(*longp);

  const float SC[4] = {L2E, L2E, 2.f * L2E, L2E};
  float hhv[4];
  #pragma unroll
  for (int g = 0; g < 4; ++g)
    hhv[g] = hh[(size_t)b * 1024 + g * HDIM + h] * SC[g];
  const float cprev = c0[b * HDIM + h];

  // W_ih fragments (B operand), pre-scaled by SC[g]
  s16x8 wf[4][2];
  #pragma unroll
  for (int g = 0; g < 4; ++g) {
    const float4* wrow = (const float4*)(Wih + (size_t)(g * HDIM + h) * DDIM);
    #pragma unroll
    for (int ks = 0; ks < 2; ++ks)
      wf[g][ks] = pack_bf8s(wrow[kg * 2 + ks * 8], wrow[kg * 2 + ks * 8 + 1], SC[g]);
  }

  // A fragments: row = t0w + tb + col, k = kg*8 + j (+32); 1-deep prefetch
  const int t0w = tq * 128;
  const float* arow = xb + (size_t)(t0w + col) * DDIM + kg * 8;

  float4 nxt0 = *(const float4*)(arow + 0);
  float4 nxt1 = *(const float4*)(arow + 4);
  float4 nxt2 = *(const float4*)(arow + 32);
  float4 nxt3 = *(const float4*)(arow + 36);
  s16x8 a0 = pack_bf8(nxt0, nxt1);
  s16x8 a1 = pack_bf8(nxt2, nxt3);
  // lanes 0..15 hold x[t0w+tb+lane][0..3] in q0 -> raw (w0*long, w1) pair
  float w0c = nxt0.x, w1c = nxt0.y;
  if (tq == 0 && lane == 0) { w0c = 0.f; w1c = 0.f; }   // t=0 mask (tile 0)

  float s0h = 0.f, s1h = 0.f, s0c = 0.f, s1c = 0.f;

  for (int tb = 0; tb < 128; tb += 16) {
    const bool has_next = (tb + 16) < 128;
    if (has_next) {
      const float* p = arow + (size_t)(tb + 16) * DDIM;
      nxt0 = *(const float4*)(p + 0);
      nxt1 = *(const float4*)(p + 4);
      nxt2 = *(const float4*)(p + 32);
      nxt3 = *(const float4*)(p + 36);
    }

    f32x4 acc[4];
    #pragma unroll
    for (int g = 0; g < 4; ++g) {
      f32x4 zc = {hhv[g], hhv[g], hhv[g], hhv[g]};  // bias+hh folded into C
      zc = __builtin_amdgcn_mfma_f32_16x16x32_bf16(a0, wf[g][0], zc, 0, 0, 0);
      zc = __builtin_amdgcn_mfma_f32_16x16x32_bf16(a1, wf[g][1], zc, 0, 0, 0);
      acc[g] = zc;
    }

    #pragma unroll
    for (int r = 0; r < 4; ++r) {
      float wx = __shfl(w0c, kg * 4 + r, 64);
      float wy = __shfl(w1c, kg * 4 + r, 64);
      float ig = rcpf(1.f + EXP2(-acc[0][r]));
      float fg = rcpf(1.f + EXP2(-acc[1][r]));
      float gg = fmaf(-2.f, rcpf(EXP2(acc[2][r]) + 1.f), 1.f);
      float og = rcpf(1.f + EXP2(-acc[3][r]));
      float cc = fmaf(fg, cprev, ig * gg);
      float th = fmaf(-2.f, rcpf(EXP2(cc * (2.f * L2E)) + 1.f), 1.f);
      float hv = og * th;
      s0h = fmaf(hv, wx, s0h); s1h = fmaf(hv, wy, s1h);
      s0c = fmaf(cc, wx, s0c); s1c = fmaf(cc, wy, s1c);
    }

    if (has_next) {
      a0 = pack_bf8(nxt0, nxt1);
      a1 = pack_bf8(nxt2, nxt3);
      w0c = nxt0.x; w1c = nxt0.y;       // rows >= 16: no t=0 mask needed
    }
  }

  // reduce over the 4 k-groups (lanes sharing col)
  s0h += __shfl_xor(s0h, 16, 64); s0h += __shfl_xor(s0h, 32, 64);
  s1h += __shfl_xor(s1h, 16, 64); s1h += __shfl_xor(s1h, 32, 64);
  s0c += __shfl_xor(s0c, 16, 64); s0c += __shfl_xor(s0c, 32, 64);
  s1c += __shfl_xor(s1c, 16, 64); s1c += __shfl_xor(s1c, 32, 64);

  if (kg == 0) {
    red[wave * 64 +  0 + col] = s0h * inv_long;   // /long folded here
    red[wave * 64 + 16 + col] = s1h;
    red[wave * 64 + 32 + col] = s0c * inv_long;
    red[wave * 64 + 48 + col] = s1c;
  }
  __syncthreads();

  // combine the 4 t-quarters per h-slice (waves {hp, 2+hp, 4+hp, 6+hp})
  if (tid < 128) {
    const int hp2 = tid >> 6;
    const int q   = (tid >> 4) & 3;
    const int cc2 = tid & 15;
    const int o   = q * 16 + cc2;
    float s = red[(0 + hp2) * 64 + o] + red[(2 + hp2) * 64 + o] +
              red[(4 + hp2) * 64 + o] + red[(6 + hp2) * 64 + o];
    const int h2 = hcq * 32 + hp2 * 16 + cc2;
    sbuf[(size_t)q * BH + b * HDIM + h2] = s;
  }
}

// Grid: 128 blocks (b), 256 threads. W0/W1 sums (once per b) + GEMV epilogue.
__global__ __launch_bounds__(256) void out_kernel(
    const float* __restrict__ x, const float* __restrict__ f1w,
    const float* __restrict__ f1b, const float* __restrict__ f2w,
    const float* __restrict__ f2b, const int* __restrict__ longp,
    const float* __restrict__ sbuf, float* __restrict__ out)
{
  const int b = blockIdx.x, tid = threadIdx.x;
  __shared__ float s0h[256], s1h[256], s0c[256], s1c[256];
  __shared__ float wsum[8];
  const float* xb = x + (size_t)b * (TDIM * DDIM);

  s0h[tid] = sbuf[(size_t)0 * BH + b * HDIM + tid];
  s1h[tid] = sbuf[(size_t)1 * BH + b * HDIM + tid];
  s0c[tid] = sbuf[(size_t)2 * BH + b * HDIM + tid];
  s1c[tid] = sbuf[(size_t)3 * BH + b * HDIM + tid];

  float w0p = 0.f, w1p = 0.f;
  for (int t = tid; t < TDIM; t += 256) {
    float2 v = *(const float2*)(xb + (size_t)t * DDIM);
    w0p += v.x; w1p += v.y;
  }
  #pragma unroll
  for (int off = 1; off < 64; off <<= 1) {
    w0p += __shfl_xor(w0p, off, 64);
    w1p += __shfl_xor(w1p, off, 64);
  }
  if ((tid & 63) == 0) { wsum[tid >> 6] = w0p; wsum[4 + (tid >> 6)] = w1p; }
  __syncthreads();

  const float inv_long = 1.0f / (float)(*longp);
  const float W0 = (wsum[0] + wsum[1] + wsum[2] + wsum[3]) * inv_long; // all t
  const float W1 = (wsum[4] + wsum[5] + wsum[6] + wsum[7]);

  float rh, rc;
  if (tid < 128) {                       // "first": f1_w with w0-weighted sums
    const float4* wr = (const float4*)(f1w + (size_t)tid * HDIM);
    float ah = 0.f, ac = 0.f;
    #pragma unroll 8
    for (int k = 0; k < HDIM / 4; ++k) {
      float4 w = wr[k];
      ah += w.x * s0h[4*k] + w.y * s0h[4*k+1] + w.z * s0h[4*k+2] + w.w * s0h[4*k+3];
      ac += w.x * s0c[4*k] + w.y * s0c[4*k+1] + w.z * s0c[4*k+2] + w.w * s0c[4*k+3];
    }
    const float bb = f1b[tid];
    rh = ah + bb * W0;
    rc = ac + bb * W0;
  } else {                               // "second": f2_w with w1-weighted sums
    const int k0 = tid - 128;
    const float4* wr = (const float4*)(f2w + (size_t)k0 * HDIM);
    float ah = 0.f, ac = 0.f;
    #pragma unroll 8
    for (int k = 0; k < HDIM / 4; ++k) {
      float4 w = wr[k];
      ah += w.x * s1h[4*k] + w.y * s1h[4*k+1] + w.z * s1h[4*k+2] + w.w * s1h[4*k+3];
      ac += w.x * s1c[4*k] + w.y * s1c[4*k+1] + w.z * s1c[4*k+2] + w.w * s1c[4*k+3];
    }
    const float bb = f2b[k0];
    rh = ah + bb * W1;
    rc = ac + bb * W1;
  }
  out[b * HDIM + tid] = rh;                      // agg(h_all) -> (1,B,256)
  out[BDIM * HDIM + b * HDIM + tid] = rc;        // agg(c_all)
}

extern "C" void kernel_launch(void* const* d_in, const int* in_sizes, int n_in,
                              void* d_out, int out_size, void* d_ws, size_t ws_size,
                              hipStream_t stream) {
  const float* x   = (const float*)d_in[0];
  const float* h0  = (const float*)d_in[1];
  const float* c0  = (const float*)d_in[2];
  const float* Wih = (const float*)d_in[3];
  const float* Whh = (const float*)d_in[4];
  const float* bih = (const float*)d_in[5];
  const float* bhh = (const float*)d_in[6];
  const float* f1w = (const float*)d_in[7];
  const float* f1b = (const float*)d_in[8];
  const float* f2w = (const float*)d_in[9];
  const float* f2b = (const float*)d_in[10];
  const int*  longp = (const int*)d_in[11];
  float* out  = (float*)d_out;
  float* sbuf = (float*)d_ws;   // planes 512KB + hh 512KB

  hh2_kernel<<<64, 256, 0, stream>>>(h0, Whh, bih, bhh, sbuf + HH_OFF);
  dim3 g1(BDIM, 8);
  fused_lstm<<<g1, 512, 0, stream>>>(x, c0, Wih, longp, sbuf);
  out_kernel<<<BDIM, 256, 0, stream>>>(x, f1w, f1b, f2w, f2b, longp, sbuf, out);
}

// Round 13
// 66.361 us; speedup vs baseline: 1.1843x; 1.1843x over previous
//
#include <hip/hip_runtime.h>

#define BDIM 128
#define TDIM 512
#define DDIM 64
#define HDIM 256
#define BH   (BDIM * HDIM)            // 32768
#define HH_OFF (4 * BH)               // hh: B x 1024 after the 4 partial planes

typedef short s16x8 __attribute__((ext_vector_type(8)));
typedef float f32x4 __attribute__((ext_vector_type(4)));

#if __has_builtin(__builtin_amdgcn_exp2f)
#define EXP2(x) __builtin_amdgcn_exp2f(x)
#else
#define EXP2(x) exp2f(x)
#endif
#define L2E 1.44269504f

__device__ __forceinline__ float rcpf(float x) { return __builtin_amdgcn_rcpf(x); }

__device__ __forceinline__ short f2bf(float f) {
  __bf16 b = (__bf16)f;
  return __builtin_bit_cast(short, b);
}

__device__ __forceinline__ s16x8 pack_bf8(float4 lo, float4 hi) {
  s16x8 v;
  v[0] = f2bf(lo.x); v[1] = f2bf(lo.y); v[2] = f2bf(lo.z); v[3] = f2bf(lo.w);
  v[4] = f2bf(hi.x); v[5] = f2bf(hi.y); v[6] = f2bf(hi.z); v[7] = f2bf(hi.w);
  return v;
}

__device__ __forceinline__ s16x8 pack_bf8s(float4 lo, float4 hi, float s) {
  s16x8 v;
  v[0] = f2bf(lo.x*s); v[1] = f2bf(lo.y*s); v[2] = f2bf(lo.z*s); v[3] = f2bf(lo.w*s);
  v[4] = f2bf(hi.x*s); v[5] = f2bf(hi.y*s); v[6] = f2bf(hi.z*s); v[7] = f2bf(hi.w*s);
  return v;
}

// hh = h0 @ Whh^T + bih + bhh via MFMA — 67 MFLOP, 8 MFMA/wave, ZERO LDS.
// (R12's LDS-staged VALU GEMV was LDS-throughput-bound at ~20us: 1024
//  ds_read_b128/wave x 12cyc x 4 waves/CU. Matrix cores do it for free.)
// Grid (8,16) x 256 thr: block = (16 b's, 64 cols); wave = 16-col subtile.
// A[m][k]: m=b-local (lane&15), k=kg*8+j (+32/step) — contiguous h0 row read.
// B[k][n]: n=colw (lane&15), same contiguous Whh row pattern as fused's Wih.
// C: col=lane&15 (n), row=(lane>>4)*4+r (m).
__global__ __launch_bounds__(256) void hh_mfma_kernel(
    const float* __restrict__ h0, const float* __restrict__ Whh,
    const float* __restrict__ bih, const float* __restrict__ bhh,
    float* __restrict__ hh)
{
  const int bt   = blockIdx.x;          // 0..7  (16 b's)
  const int nt   = blockIdx.y;          // 0..15 (64 cols)
  const int tid  = threadIdx.x;
  const int wave = tid >> 6;            // 0..3
  const int lane = tid & 63;
  const int col  = lane & 15;
  const int kg   = lane >> 4;           // 0..3
  const int b0   = bt * 16;
  const int colw = nt * 64 + wave * 16 + col;

  const float bias = bih[colw] + bhh[colw];

  const float* arow = h0  + (size_t)(b0 + col) * HDIM + kg * 8;
  const float* brow = Whh + (size_t)colw * HDIM + kg * 8;

  f32x4 acc = {0.f, 0.f, 0.f, 0.f};
  #pragma unroll
  for (int s = 0; s < 8; ++s) {
    float4 a0 = *(const float4*)(arow + s * 32);
    float4 a1 = *(const float4*)(arow + s * 32 + 4);
    float4 q0 = *(const float4*)(brow + s * 32);
    float4 q1 = *(const float4*)(brow + s * 32 + 4);
    acc = __builtin_amdgcn_mfma_f32_16x16x32_bf16(
        pack_bf8(a0, a1), pack_bf8(q0, q1), acc, 0, 0, 0);
  }

  #pragma unroll
  for (int r = 0; r < 4; ++r) {
    const int m = kg * 4 + r;           // b-local row
    hh[(size_t)(b0 + m) * 1024 + colw] = acc[r] + bias;
  }
}

// Grid: (128, 8), 512 threads = 8 waves, zero in-loop barriers.
// EXACT R8/R12 structure (fastest measured fused body, 51.7us): hh from
// global (precomputed), w0/w1 via __shfl from A-tile registers, 1-deep prefetch.
__global__ __launch_bounds__(512, 4) void fused_lstm(
    const float* __restrict__ x, const float* __restrict__ c0,
    const float* __restrict__ Wih, const int* __restrict__ longp,
    float* __restrict__ sbuf)
{
  const int b    = blockIdx.x;
  const int hcq  = blockIdx.y;          // 0..7
  const int tid  = threadIdx.x;
  const int wave = tid >> 6;            // 0..7
  const int lane = tid & 63;
  const int col  = lane & 15;
  const int kg   = lane >> 4;           // 0..3
  const int hp   = wave & 1;
  const int tq   = wave >> 1;           // 0..3
  const int h    = hcq * 32 + hp * 16 + col;

  __shared__ float red[8 * 64];

  const float* hh = sbuf + HH_OFF;
  const float* xb = x + (size_t)b * (TDIM * DDIM);
  const float inv_long = 1.0f / (float)(*longp);

  const float SC[4] = {L2E, L2E, 2.f * L2E, L2E};
  float hhv[4];
  #pragma unroll
  for (int g = 0; g < 4; ++g)
    hhv[g] = hh[(size_t)b * 1024 + g * HDIM + h] * SC[g];
  const float cprev = c0[b * HDIM + h];

  // W_ih fragments (B operand), pre-scaled by SC[g]
  s16x8 wf[4][2];
  #pragma unroll
  for (int g = 0; g < 4; ++g) {
    const float4* wrow = (const float4*)(Wih + (size_t)(g * HDIM + h) * DDIM);
    #pragma unroll
    for (int ks = 0; ks < 2; ++ks)
      wf[g][ks] = pack_bf8s(wrow[kg * 2 + ks * 8], wrow[kg * 2 + ks * 8 + 1], SC[g]);
  }

  // A fragments: row = t0w + tb + col, k = kg*8 + j (+32); 1-deep prefetch
  const int t0w = tq * 128;
  const float* arow = xb + (size_t)(t0w + col) * DDIM + kg * 8;

  float4 nxt0 = *(const float4*)(arow + 0);
  float4 nxt1 = *(const float4*)(arow + 4);
  float4 nxt2 = *(const float4*)(arow + 32);
  float4 nxt3 = *(const float4*)(arow + 36);
  s16x8 a0 = pack_bf8(nxt0, nxt1);
  s16x8 a1 = pack_bf8(nxt2, nxt3);
  // lanes 0..15 hold x[t0w+tb+lane][0..3] in q0 -> raw (w0*long, w1) pair
  float w0c = nxt0.x, w1c = nxt0.y;
  if (tq == 0 && lane == 0) { w0c = 0.f; w1c = 0.f; }   // t=0 mask (tile 0)

  float s0h = 0.f, s1h = 0.f, s0c = 0.f, s1c = 0.f;

  for (int tb = 0; tb < 128; tb += 16) {
    const bool has_next = (tb + 16) < 128;
    if (has_next) {
      const float* p = arow + (size_t)(tb + 16) * DDIM;
      nxt0 = *(const float4*)(p + 0);
      nxt1 = *(const float4*)(p + 4);
      nxt2 = *(const float4*)(p + 32);
      nxt3 = *(const float4*)(p + 36);
    }

    f32x4 acc[4];
    #pragma unroll
    for (int g = 0; g < 4; ++g) {
      f32x4 zc = {hhv[g], hhv[g], hhv[g], hhv[g]};  // bias+hh folded into C
      zc = __builtin_amdgcn_mfma_f32_16x16x32_bf16(a0, wf[g][0], zc, 0, 0, 0);
      zc = __builtin_amdgcn_mfma_f32_16x16x32_bf16(a1, wf[g][1], zc, 0, 0, 0);
      acc[g] = zc;
    }

    #pragma unroll
    for (int r = 0; r < 4; ++r) {
      float wx = __shfl(w0c, kg * 4 + r, 64);
      float wy = __shfl(w1c, kg * 4 + r, 64);
      float ig = rcpf(1.f + EXP2(-acc[0][r]));
      float fg = rcpf(1.f + EXP2(-acc[1][r]));
      float gg = fmaf(-2.f, rcpf(EXP2(acc[2][r]) + 1.f), 1.f);
      float og = rcpf(1.f + EXP2(-acc[3][r]));
      float cc = fmaf(fg, cprev, ig * gg);
      float th = fmaf(-2.f, rcpf(EXP2(cc * (2.f * L2E)) + 1.f), 1.f);
      float hv = og * th;
      s0h = fmaf(hv, wx, s0h); s1h = fmaf(hv, wy, s1h);
      s0c = fmaf(cc, wx, s0c); s1c = fmaf(cc, wy, s1c);
    }

    if (has_next) {
      a0 = pack_bf8(nxt0, nxt1);
      a1 = pack_bf8(nxt2, nxt3);
      w0c = nxt0.x; w1c = nxt0.y;       // rows >= 16: no t=0 mask needed
    }
  }

  // reduce over the 4 k-groups (lanes sharing col)
  s0h += __shfl_xor(s0h, 16, 64); s0h += __shfl_xor(s0h, 32, 64);
  s1h += __shfl_xor(s1h, 16, 64); s1h += __shfl_xor(s1h, 32, 64);
  s0c += __shfl_xor(s0c, 16, 64); s0c += __shfl_xor(s0c, 32, 64);
  s1c += __shfl_xor(s1c, 16, 64); s1c += __shfl_xor(s1c, 32, 64);

  if (kg == 0) {
    red[wave * 64 +  0 + col] = s0h * inv_long;   // /long folded here
    red[wave * 64 + 16 + col] = s1h;
    red[wave * 64 + 32 + col] = s0c * inv_long;
    red[wave * 64 + 48 + col] = s1c;
  }
  __syncthreads();

  // combine the 4 t-quarters per h-slice (waves {hp, 2+hp, 4+hp, 6+hp})
  if (tid < 128) {
    const int hp2 = tid >> 6;
    const int q   = (tid >> 4) & 3;
    const int cc2 = tid & 15;
    const int o   = q * 16 + cc2;
    float s = red[(0 + hp2) * 64 + o] + red[(2 + hp2) * 64 + o] +
              red[(4 + hp2) * 64 + o] + red[(6 + hp2) * 64 + o];
    const int h2 = hcq * 32 + hp2 * 16 + cc2;
    sbuf[(size_t)q * BH + b * HDIM + h2] = s;
  }
}

// Grid: 128 blocks (b), 256 threads. W0/W1 sums (once per b) + GEMV epilogue.
__global__ __launch_bounds__(256) void out_kernel(
    const float* __restrict__ x, const float* __restrict__ f1w,
    const float* __restrict__ f1b, const float* __restrict__ f2w,
    const float* __restrict__ f2b, const int* __restrict__ longp,
    const float* __restrict__ sbuf, float* __restrict__ out)
{
  const int b = blockIdx.x, tid = threadIdx.x;
  __shared__ float s0h[256], s1h[256], s0c[256], s1c[256];
  __shared__ float wsum[8];
  const float* xb = x + (size_t)b * (TDIM * DDIM);

  s0h[tid] = sbuf[(size_t)0 * BH + b * HDIM + tid];
  s1h[tid] = sbuf[(size_t)1 * BH + b * HDIM + tid];
  s0c[tid] = sbuf[(size_t)2 * BH + b * HDIM + tid];
  s1c[tid] = sbuf[(size_t)3 * BH + b * HDIM + tid];

  float w0p = 0.f, w1p = 0.f;
  for (int t = tid; t < TDIM; t += 256) {
    float2 v = *(const float2*)(xb + (size_t)t * DDIM);
    w0p += v.x; w1p += v.y;
  }
  #pragma unroll
  for (int off = 1; off < 64; off <<= 1) {
    w0p += __shfl_xor(w0p, off, 64);
    w1p += __shfl_xor(w1p, off, 64);
  }
  if ((tid & 63) == 0) { wsum[tid >> 6] = w0p; wsum[4 + (tid >> 6)] = w1p; }
  __syncthreads();

  const float inv_long = 1.0f / (float)(*longp);
  const float W0 = (wsum[0] + wsum[1] + wsum[2] + wsum[3]) * inv_long; // all t
  const float W1 = (wsum[4] + wsum[5] + wsum[6] + wsum[7]);

  float rh, rc;
  if (tid < 128) {                       // "first": f1_w with w0-weighted sums
    const float4* wr = (const float4*)(f1w + (size_t)tid * HDIM);
    float ah = 0.f, ac = 0.f;
    #pragma unroll 8
    for (int k = 0; k < HDIM / 4; ++k) {
      float4 w = wr[k];
      ah += w.x * s0h[4*k] + w.y * s0h[4*k+1] + w.z * s0h[4*k+2] + w.w * s0h[4*k+3];
      ac += w.x * s0c[4*k] + w.y * s0c[4*k+1] + w.z * s0c[4*k+2] + w.w * s0c[4*k+3];
    }
    const float bb = f1b[tid];
    rh = ah + bb * W0;
    rc = ac + bb * W0;
  } else {                               // "second": f2_w with w1-weighted sums
    const int k0 = tid - 128;
    const float4* wr = (const float4*)(f2w + (size_t)k0 * HDIM);
    float ah = 0.f, ac = 0.f;
    #pragma unroll 8
    for (int k = 0; k < HDIM / 4; ++k) {
      float4 w = wr[k];
      ah += w.x * s1h[4*k] + w.y * s1h[4*k+1] + w.z * s1h[4*k+2] + w.w * s1h[4*k+3];
      ac += w.x * s1c[4*k] + w.y * s1c[4*k+1] + w.z * s1c[4*k+2] + w.w * s1c[4*k+3];
    }
    const float bb = f2b[k0];
    rh = ah + bb * W1;
    rc = ac + bb * W1;
  }
  out[b * HDIM + tid] = rh;                      // agg(h_all) -> (1,B,256)
  out[BDIM * HDIM + b * HDIM + tid] = rc;        // agg(c_all)
}

extern "C" void kernel_launch(void* const* d_in, const int* in_sizes, int n_in,
                              void* d_out, int out_size, void* d_ws, size_t ws_size,
                              hipStream_t stream) {
  const float* x   = (const float*)d_in[0];
  const float* h0  = (const float*)d_in[1];
  const float* c0  = (const float*)d_in[2];
  const float* Wih = (const float*)d_in[3];
  const float* Whh = (const float*)d_in[4];
  const float* bih = (const float*)d_in[5];
  const float* bhh = (const float*)d_in[6];
  const float* f1w = (const float*)d_in[7];
  const float* f1b = (const float*)d_in[8];
  const float* f2w = (const float*)d_in[9];
  const float* f2b = (const float*)d_in[10];
  const int*  longp = (const int*)d_in[11];
  float* out  = (float*)d_out;
  float* sbuf = (float*)d_ws;   // planes 512KB + hh 512KB

  dim3 gh(8, 16);
  hh_mfma_kernel<<<gh, 256, 0, stream>>>(h0, Whh, bih, bhh, sbuf + HH_OFF);
  dim3 g1(BDIM, 8);
  fused_lstm<<<g1, 512, 0, stream>>>(x, c0, Wih, longp, sbuf);
  out_kernel<<<BDIM, 256, 0, stream>>>(x, f1w, f1b, f2w, f2b, longp, sbuf, out);
}